// Round 10
// baseline (152.528 us; speedup 1.0000x reference)
//
#include <hip/hip_runtime.h>
#include <math.h>

#define NPLANES 24   // B*C = 8*3
#define FINF 3.402823466e38f

__host__ __device__ __forceinline__ int d_off(int li) {
    return 2097152 - (2097152 >> (2 * li));
}

__device__ __forceinline__ int refl(int v, int S) {
    if (v < 0) v = -v;
    if (v >= S) v = 2 * S - 2 - v;
    return v;
}

// ---- shuffle reductions (no LDS, no barriers) ----
__device__ __forceinline__ void wminmax64(float& mn, float& mx) {
#pragma unroll
    for (int o = 32; o > 0; o >>= 1) {
        mn = fminf(mn, __shfl_xor(mn, o, 64));
        mx = fmaxf(mx, __shfl_xor(mx, o, 64));
    }
}
__device__ __forceinline__ float wsumx64(float v) {
#pragma unroll
    for (int o = 32; o > 0; o >>= 1) v += __shfl_xor(v, o, 64);
    return v;
}
__device__ __forceinline__ void wminmax16(float& mn, float& mx) {
#pragma unroll
    for (int o = 8; o > 0; o >>= 1) {
        mn = fminf(mn, __shfl_xor(mn, o, 16));
        mx = fmaxf(mx, __shfl_xor(mx, o, 16));
    }
}

// 6-tap separable collapsed pyrdown stencil on an LDS plane of size SxS.
__device__ __forceinline__ float stencil6(const float* s, int S, int i, int j) {
    const float w[6] = {1.f, 5.f, 10.f, 10.f, 5.f, 1.f};
    int rx[6];
#pragma unroll
    for (int b = 0; b < 6; ++b) rx[b] = refl(2 * j - 2 + b, S);
    float acc = 0.f;
#pragma unroll
    for (int a = 0; a < 6; ++a) {
        int ry = refl(2 * i - 2 + a, S);
        const float* rp = s + ry * S;
        float r = 0.f;
#pragma unroll
        for (int b = 0; b < 6; ++b) r += w[b] * rp[rx[b]];
        acc += w[a] * r;
    }
    return acc * (1.f / 1024.f);
}

// L1 pyrdown: x (512^2) -> pyr1 (256^2). Block = 32x32 output tile.
__global__ __launch_bounds__(256) void pyrdown_l1(const float* __restrict__ in,
                                                  float* __restrict__ out) {
    constexpr int IS = 512, SO = 256, TO = 32, TI = 68, TPA = 8;
    __shared__ float sIn[TI * TI];
    __shared__ float sH[TI * TO];
    const int tid = threadIdx.x;
    const int p = blockIdx.x / (TPA * TPA);
    const int t = blockIdx.x % (TPA * TPA);
    const int ty = t / TPA, tx = t % TPA;
    const int oy = ty * TO, ox = tx * TO;
    const int iy = 2 * oy - 2, ix = 2 * ox - 2;
    const float* ip = in + (size_t)p * IS * IS;

    for (int k = tid; k < TI * TI; k += 256) {
        int r = k / TI, c = k - r * TI;
        sIn[k] = ip[refl(iy + r, IS) * IS + refl(ix + c, IS)];
    }
    __syncthreads();
    for (int k = tid; k < TI * 8; k += 256) {
        int r = k >> 3, jq = k & 7;
        const float4* rp = (const float4*)(sIn + r * TI + 8 * jq);
        float4 v0 = rp[0], v1 = rp[1], v2 = rp[2];
        float4 o;
        o.x = v0.x + 5.f * v0.y + 10.f * v0.z + 10.f * v0.w + 5.f * v1.x + v1.y;
        o.y = v0.z + 5.f * v0.w + 10.f * v1.x + 10.f * v1.y + 5.f * v1.z + v1.w;
        o.z = v1.x + 5.f * v1.y + 10.f * v1.z + 10.f * v1.w + 5.f * v2.x + v2.y;
        o.w = v1.z + 5.f * v1.w + 10.f * v2.x + 10.f * v2.y + 5.f * v2.z + v2.w;
        *(float4*)(sH + r * TO + 4 * jq) = o;
    }
    __syncthreads();
    {
        int i = tid >> 3, jq = tid & 7;
        const float* base = sH + (2 * i) * TO + 4 * jq;
        float4 r0 = *(const float4*)(base);
        float4 r1 = *(const float4*)(base + TO);
        float4 r2 = *(const float4*)(base + 2 * TO);
        float4 r3 = *(const float4*)(base + 3 * TO);
        float4 r4 = *(const float4*)(base + 4 * TO);
        float4 r5 = *(const float4*)(base + 5 * TO);
        float4 o;
        o.x = (r0.x + 5.f * r1.x + 10.f * r2.x + 10.f * r3.x + 5.f * r4.x + r5.x) * (1.f / 1024.f);
        o.y = (r0.y + 5.f * r1.y + 10.f * r2.y + 10.f * r3.y + 5.f * r4.y + r5.y) * (1.f / 1024.f);
        o.z = (r0.z + 5.f * r1.z + 10.f * r2.z + 10.f * r3.z + 5.f * r4.z + r5.z) * (1.f / 1024.f);
        o.w = (r0.w + 5.f * r1.w + 10.f * r2.w + 10.f * r3.w + 5.f * r4.w + r5.w) * (1.f / 1024.f);
        *(float4*)(out + (size_t)p * SO * SO + (size_t)(oy + i) * SO + ox + 4 * jq) = o;
    }
}

// Fused L2+L3 pyrdown with last-arriver tail. Block = one 16x16 pyr3 tile;
// grid = 24 planes x 16 tiles. Produces pyr3 tile, d0/d1 regions, li=0/1 tile
// stats. The LAST block of each plane (device-scope atomic) then runs the
// whole pyr4..8 chain + all A/B stats, overlapped with other planes' tiles.
__global__ __launch_bounds__(256) void pyrdown23(const float* __restrict__ pyr1,
                                                 float* __restrict__ pyr3,
                                                 float* __restrict__ dBase,
                                                 float* __restrict__ tmin0,
                                                 float* __restrict__ tmax0,
                                                 float* __restrict__ tmin1,
                                                 float* __restrict__ tmax1,
                                                 float* __restrict__ A,
                                                 float* __restrict__ B,
                                                 int* __restrict__ ctr) {
    __shared__ float smem[10912];
    __shared__ int sLast;
    // phase-1 carve
    float* sIn  = smem;           // 76x76 = 5776
    float* sH1  = smem + 5776;    // 76x36 = 2736
    float* sP2  = smem + 8512;    // 36x36 = 1296
    float* sH2  = smem + 9808;    // 36x16 = 576
    float* sP3t = smem + 10384;   // 16x16 = 256
    const int tid = threadIdx.x;
    const int p = blockIdx.x >> 4;
    const int t = blockIdx.x & 15;
    const int t3y = t >> 2, t3x = t & 3;
    const int oy3 = t3y * 16, ox3 = t3x * 16;
    const int oy2 = 2 * oy3, ox2 = 2 * ox3;
    const int py0 = oy2 - 2, px0 = ox2 - 2;
    const int iy0 = 2 * py0 - 2, ix0 = 2 * px0 - 2;
    const float* ip = pyr1 + (size_t)p * 65536;

    for (int k = tid; k < 5776; k += 256) {
        int r = k / 76, c = k - r * 76;
        sIn[k] = ip[refl(iy0 + r, 256) * 256 + refl(ix0 + c, 256)];
    }
    __syncthreads();
    for (int k = tid; k < 2736; k += 256) {
        int r = k / 36, c2 = k - r * 36;
        const float* rp = sIn + r * 76 + 2 * c2;
        sH1[k] = rp[0] + 5.f * rp[1] + 10.f * rp[2] + 10.f * rp[3] + 5.f * rp[4] + rp[5];
    }
    __syncthreads();
    for (int k = tid; k < 1296; k += 256) {
        int r2 = k / 36, c2 = k - r2 * 36;
        const float* cp = sH1 + 2 * r2 * 36 + c2;
        sP2[k] = (cp[0] + 5.f * cp[36] + 10.f * cp[72] + 10.f * cp[108] +
                  5.f * cp[144] + cp[180]) * (1.f / 1024.f);
    }
    __syncthreads();
    for (int k = tid; k < 576; k += 256) {
        int r2 = k >> 4, c3 = k & 15;
        int gb = 2 * (ox3 + c3) - 2;
        const float* rp = sP2 + r2 * 36;
        sH2[k] = rp[refl(gb, 128) - px0] + 5.f * rp[refl(gb + 1, 128) - px0] +
                 10.f * rp[refl(gb + 2, 128) - px0] + 10.f * rp[refl(gb + 3, 128) - px0] +
                 5.f * rp[refl(gb + 4, 128) - px0] + rp[refl(gb + 5, 128) - px0];
    }
    __syncthreads();
    {
        int i3 = tid >> 4, c3 = tid & 15;
        int gb = 2 * (oy3 + i3) - 2;
        float s = sH2[(refl(gb, 128) - py0) * 16 + c3] +
                  5.f * sH2[(refl(gb + 1, 128) - py0) * 16 + c3] +
                  10.f * sH2[(refl(gb + 2, 128) - py0) * 16 + c3] +
                  10.f * sH2[(refl(gb + 3, 128) - py0) * 16 + c3] +
                  5.f * sH2[(refl(gb + 4, 128) - py0) * 16 + c3] +
                  sH2[(refl(gb + 5, 128) - py0) * 16 + c3];
        float v = s * (1.f / 1024.f);
        sP3t[tid] = v;
        pyr3[(size_t)p * 4096 + (size_t)(oy3 + i3) * 64 + ox3 + c3] = v;
    }
    __syncthreads();
    // d0 = |pyr1 - up(pyr2)|, 4x4 block/thread; 16x16 stats tile = 16 threads
    {
        float* d0g = dBase + (size_t)p * 65536;
        int ti = tid >> 4, si = tid & 15;
        int tr = ti >> 2, tc = ti & 3;
        int y0 = tr * 16 + (si >> 2) * 4, x0 = tc * 16 + (si & 3) * 4;
        float mn = FINF, mx = -FINF;
#pragma unroll
        for (int r = 0; r < 4; ++r) {
            int y = y0 + r;
            const float* srow = sIn + (y + 6) * 76 + x0 + 6;
            const float* prow = sP2 + ((y >> 1) + 2) * 36 + 2 + (x0 >> 1);
            float e0 = prow[0], e1 = prow[1];
            float4 dv;
            dv.x = fabsf(srow[0] - e0);
            dv.y = fabsf(srow[1] - e0);
            dv.z = fabsf(srow[2] - e1);
            dv.w = fabsf(srow[3] - e1);
            *(float4*)(d0g + (size_t)(4 * oy3 + y) * 256 + 4 * ox3 + x0) = dv;
            mn = fminf(mn, fminf(fminf(dv.x, dv.y), fminf(dv.z, dv.w)));
            mx = fmaxf(mx, fmaxf(fmaxf(dv.x, dv.y), fmaxf(dv.z, dv.w)));
        }
        wminmax16(mn, mx);
        if (si == 0) {
            int g0 = p * 256 + (t3y * 4 + tr) * 16 + (t3x * 4 + tc);
            tmin0[g0] = mn;
            tmax0[g0] = mx;
        }
    }
    // d1 = |pyr2 - up(pyr3)|, wave 0 only
    if (tid < 64) {
        float* d1g = dBase + d_off(1) + (size_t)p * 16384;
        int ti = tid >> 4, si = tid & 15;
        int tr = ti >> 1, tc = ti & 1;
        int y0 = tr * 16 + (si >> 2) * 4, x0 = tc * 16 + (si & 3) * 4;
        float mn = FINF, mx = -FINF;
#pragma unroll
        for (int r = 0; r < 4; ++r) {
            int y = y0 + r;
            const float* prow = sP2 + (y + 2) * 36 + 2 + x0;
            const float* qrow = sP3t + (y >> 1) * 16 + (x0 >> 1);
            float e0 = qrow[0], e1 = qrow[1];
            float4 dv;
            dv.x = fabsf(prow[0] - e0);
            dv.y = fabsf(prow[1] - e0);
            dv.z = fabsf(prow[2] - e1);
            dv.w = fabsf(prow[3] - e1);
            *(float4*)(d1g + (size_t)(oy2 + y) * 128 + ox2 + x0) = dv;
            mn = fminf(mn, fminf(fminf(dv.x, dv.y), fminf(dv.z, dv.w)));
            mx = fmaxf(mx, fmaxf(fmaxf(dv.x, dv.y), fmaxf(dv.z, dv.w)));
        }
        wminmax16(mn, mx);
        if (si == 0) {
            int g1 = p * 64 + (t3y * 2 + tr) * 8 + (t3x * 2 + tc);
            tmin1[g1] = mn;
            tmax1[g1] = mx;
        }
    }

    // ---- last-arriver gate (device-scope release/acquire) ----
    __syncthreads();
    __threadfence();
    if (tid == 0) sLast = (atomicAdd(&ctr[p], 1) == 15);
    __syncthreads();
    if (!sLast) return;
    __threadfence();   // acquire: invalidate stale cached lines before reads

    // ---- tail: pyr4..8 chain + all stats, 256 threads, LDS re-carved ----
    float* sP3 = smem;            // 4096
    float* sd2 = smem + 4096;     // 4096
    float* sp4 = smem + 8192;     // 1024
    float* sd3 = smem + 9216;     // 1024
    float* sp5 = smem + 10240;    // 256
    float* sd4 = smem + 10496;    // 256
    float* sp6 = smem + 10752;    // 64
    float* sd5 = smem + 10816;    // 64
    float* sp7 = smem + 10880;    // 16
    float* sd6 = smem + 10896;    // 16

    for (int k = tid; k < 1024; k += 256)
        ((float4*)sP3)[k] = ((const float4*)(pyr3 + (size_t)p * 4096))[k];
    __syncthreads();
    // stage A: pyr4 (32x32) + d2 (64x64), 4 outputs/thread
    {
        float* d2g = dBase + d_off(2) + (size_t)p * 4096;
#pragma unroll
        for (int q = 0; q < 4; ++q) {
            int k = tid + 256 * q;
            int i = k >> 5, j = k & 31;
            float v = stencil6(sP3, 64, i, j);
            sp4[k] = v;
#pragma unroll
            for (int di = 0; di < 2; ++di)
#pragma unroll
                for (int dj = 0; dj < 2; ++dj) {
                    int y = 2 * i + di, x = 2 * j + dj;
                    float dv = fabsf(sP3[y * 64 + x] - v);
                    sd2[y * 64 + x] = dv;
                    d2g[y * 64 + x] = dv;
                }
        }
    }
    __syncthreads();

    const int wave = tid >> 6, lane = tid & 63;
    // ---- stage B: wave0 chain, wave1 li=1, wave2 li=0, wave3 li=2 ----
    if (wave == 0) {
        float* d3g = dBase + d_off(3) + (size_t)p * 1024;
#pragma unroll
        for (int q = 0; q < 4; ++q) {
            int k = lane + 64 * q;
            int i = k >> 4, j = k & 15;
            float v = stencil6(sp4, 32, i, j);
            sp5[k] = v;
#pragma unroll
            for (int di = 0; di < 2; ++di)
#pragma unroll
                for (int dj = 0; dj < 2; ++dj) {
                    int y = 2 * i + di, x = 2 * j + dj;
                    float dv = fabsf(sp4[y * 32 + x] - v);
                    sd3[y * 32 + x] = dv;
                    d3g[y * 32 + x] = dv;
                }
        }
        {
            int i = lane >> 3, j = lane & 7;
            float v = stencil6(sp5, 16, i, j);
            sp6[lane] = v;
            float* d4g = dBase + d_off(4) + (size_t)p * 256;
#pragma unroll
            for (int di = 0; di < 2; ++di)
#pragma unroll
                for (int dj = 0; dj < 2; ++dj) {
                    int y = 2 * i + di, x = 2 * j + dj;
                    float dv = fabsf(sp5[y * 16 + x] - v);
                    sd4[y * 16 + x] = dv;
                    d4g[y * 16 + x] = dv;
                }
        }
        if (lane < 16) {
            int i = lane >> 2, j = lane & 3;
            float v = stencil6(sp6, 8, i, j);
            sp7[lane] = v;
            float* d5g = dBase + d_off(5) + (size_t)p * 64;
#pragma unroll
            for (int di = 0; di < 2; ++di)
#pragma unroll
                for (int dj = 0; dj < 2; ++dj) {
                    int y = 2 * i + di, x = 2 * j + dj;
                    float dv = fabsf(sp6[y * 8 + x] - v);
                    sd5[y * 8 + x] = dv;
                    d5g[y * 8 + x] = dv;
                }
        }
        if (lane < 4) {
            int i = lane >> 1, j = lane & 1;
            float v = stencil6(sp7, 4, i, j);
            float* d6g = dBase + d_off(6) + (size_t)p * 16;
#pragma unroll
            for (int di = 0; di < 2; ++di)
#pragma unroll
                for (int dj = 0; dj < 2; ++dj) {
                    int y = 2 * i + di, x = 2 * j + dj;
                    float dv = fabsf(sp7[y * 4 + x] - v);
                    sd6[y * 4 + x] = dv;
                    d6g[y * 4 + x] = dv;
                }
        }
    } else if (wave == 1) {
        // li=1 reduce (64 tiles, interior 7x7)
        float tmn = tmin1[p * 64 + lane];
        float tmx = tmax1[p * 64 + lane];
        float mn = tmn, mx = tmx;
        wminmax64(mn, mx);
        float su = ((lane >> 3) < 7 && (lane & 7) < 7) ? tmx : 0.f;
        float sum = wsumx64(su);
        if (lane == 0) {
            float inv = 1.f / (mx - mn);
            float lm = (sum * (1.f / 49.f) - mn) * inv;
            float g = (1.f - lm) * (1.f - lm);
            A[1 * NPLANES + p] = g * inv;
            B[1 * NPLANES + p] = -mn * g * inv;
        }
    } else if (wave == 2) {
        // li=0 reduce (256 tiles, interior 15x15)
        float mn = FINF, mx = -FINF, su = 0.f;
#pragma unroll
        for (int q = 0; q < 4; ++q) {
            int tt = lane + 64 * q;
            float tmn = tmin0[p * 256 + tt];
            float tmx = tmax0[p * 256 + tt];
            mn = fminf(mn, tmn);
            mx = fmaxf(mx, tmx);
            if ((tt >> 4) < 15 && (tt & 15) < 15) su += tmx;
        }
        wminmax64(mn, mx);
        float sum = wsumx64(su);
        if (lane == 0) {
            float inv = 1.f / (mx - mn);
            float lm = (sum * (1.f / 225.f) - mn) * inv;
            float g = (1.f - lm) * (1.f - lm);
            A[0 * NPLANES + p] = g * inv;
            B[0 * NPLANES + p] = -mn * g * inv;
        }
    } else {
        // li=2: sd2 (64x64), interior 3x3 tiles
        const float4* sv = (const float4*)sd2;
        float mn = FINF, mx = -FINF;
#pragma unroll
        for (int q = 0; q < 16; ++q) {
            float4 v = sv[lane + 64 * q];
            mn = fminf(mn, fminf(fminf(v.x, v.y), fminf(v.z, v.w)));
            mx = fmaxf(mx, fmaxf(fmaxf(v.x, v.y), fmaxf(v.z, v.w)));
        }
        wminmax64(mn, mx);
        float tmax = -FINF;
        if (lane < 36) {
            int tt = lane >> 2, r4 = lane & 3;
            int tr = tt / 3, tc = tt % 3;
#pragma unroll
            for (int rr = 0; rr < 4; ++rr) {
                const float4* base = (const float4*)(sd2 + (16 * tr + 4 * r4 + rr) * 64 + 16 * tc);
#pragma unroll
                for (int c = 0; c < 4; ++c) {
                    float4 v = base[c];
                    tmax = fmaxf(tmax, fmaxf(fmaxf(v.x, v.y), fmaxf(v.z, v.w)));
                }
            }
        }
        tmax = fmaxf(tmax, __shfl_xor(tmax, 1, 64));
        tmax = fmaxf(tmax, __shfl_xor(tmax, 2, 64));
        float val = ((lane & 3) == 0 && lane < 36) ? tmax : 0.f;
        float s = wsumx64(val);
        if (lane == 0) {
            float inv = 1.f / (mx - mn);
            float lm = (s * (1.f / 9.f) - mn) * inv;
            float g = (1.f - lm) * (1.f - lm);
            A[2 * NPLANES + p] = g * inv;
            B[2 * NPLANES + p] = -mn * g * inv;
        }
    }
    __syncthreads();

    // ---- stage C: li=3..6, one wave each ----
    if (wave == 0) {
        // li=3: sd3 (32x32), single interior 16x16 tile
        const float4* sv = (const float4*)sd3;
        float mn = FINF, mx = -FINF;
#pragma unroll
        for (int q = 0; q < 4; ++q) {
            float4 v = sv[lane + 64 * q];
            mn = fminf(mn, fminf(fminf(v.x, v.y), fminf(v.z, v.w)));
            mx = fmaxf(mx, fmaxf(fmaxf(v.x, v.y), fmaxf(v.z, v.w)));
        }
        wminmax64(mn, mx);
        float4 e4 = sv[(lane >> 2) * 8 + (lane & 3)];
        float e = fmaxf(fmaxf(e4.x, e4.y), fmaxf(e4.z, e4.w));
        float tn = e, tm = e;
        wminmax64(tn, tm);
        if (lane == 0) {
            float inv = 1.f / (mx - mn);
            float lm = (tm - mn) * inv;
            float g = (1.f - lm) * (1.f - lm);
            A[3 * NPLANES + p] = g * inv;
            B[3 * NPLANES + p] = -mn * g * inv;
        }
    } else if (wave == 1) {
        float4 v = ((const float4*)sd4)[lane];
        float mn = fminf(fminf(v.x, v.y), fminf(v.z, v.w));
        float mx = fmaxf(fmaxf(v.x, v.y), fmaxf(v.z, v.w));
        wminmax64(mn, mx);
        if (lane == 0) {
            float inv = 1.f / (mx - mn);
            A[4 * NPLANES + p] = inv; B[4 * NPLANES + p] = -mn * inv;
        }
    } else if (wave == 2) {
        float v = sd5[lane];
        float mn = v, mx = v;
        wminmax64(mn, mx);
        if (lane == 0) {
            float inv = 1.f / (mx - mn);
            A[5 * NPLANES + p] = inv; B[5 * NPLANES + p] = -mn * inv;
        }
    } else {
        float v = (lane < 16) ? sd6[lane] : sd6[0];
        float mn = v, mx = v;
        wminmax64(mn, mx);
        if (lane == 0) {
            float inv = 1.f / (mx - mn);
            A[6 * NPLANES + p] = inv; B[6 * NPLANES + p] = -mn * inv;
        }
    }
}

// Tiled final gather, register-patch bilerp (R6-verified).
__global__ __launch_bounds__(256) void final_kernel(const float* __restrict__ dBase,
                                                    const float* __restrict__ A,
                                                    const float* __restrict__ Bc,
                                                    float* __restrict__ out) {
    __shared__ float patch[1700];
    __shared__ float sBtot;
    const int tid = threadIdx.x;
    const int b = blockIdx.x >> 6;
    const int tile = blockIdx.x & 63;
    const int yb = (tile >> 3) << 6;
    const int xb = (tile & 7) << 6;

    if (tid == 0) {
        float s = 0.f;
        for (int k = 0; k < 7; ++k)
            for (int c = 0; c < 3; ++c) s += Bc[k * NPLANES + b * 3 + c];
        sBtot = s;
    }

    const int dims[7] = {34, 18, 10, 6, 4, 3, 3};
    const int lofs[7] = {0, 1156, 1480, 1580, 1616, 1632, 1641};
    int baseY[7], baseX[7];
#pragma unroll
    for (int li = 0; li < 7; ++li) {
        const int S = 256 >> li;
        const float s = 1.f / (float)(2 << li);
        baseY[li] = (int)floorf((yb + 0.5f) * s - 0.5f);
        baseX[li] = (int)floorf((xb + 0.5f) * s - 0.5f);
        const int dim = dims[li];
        const int n = dim * dim;
        const float* d0p = dBase + d_off(li) + (size_t)(b * 3) * S * S;
        const float* d1p = d0p + S * S;
        const float* d2p = d1p + S * S;
        const float A0 = A[li * NPLANES + b * 3 + 0];
        const float A1 = A[li * NPLANES + b * 3 + 1];
        const float A2 = A[li * NPLANES + b * 3 + 2];
        for (int k = tid; k < n; k += 256) {
            int r = k / dim, c = k - r * dim;
            int sr = min(max(baseY[li] + r, 0), S - 1);
            int sc = min(max(baseX[li] + c, 0), S - 1);
            int si = sr * S + sc;
            patch[lofs[li] + k] = A0 * d0p[si] + A1 * d1p[si] + A2 * d2p[si];
        }
    }
    __syncthreads();

    const int ty = tid >> 4, tx = tid & 15;
    const int gy0 = yb + (ty << 2), gx0 = xb + (tx << 2);
    float acc[4][4];
#pragma unroll
    for (int i = 0; i < 4; ++i)
#pragma unroll
        for (int j = 0; j < 4; ++j) acc[i][j] = 0.f;

    // ---- level 0 (scale 1/2): 4x4 register patch ----
    {
        const int dim = 34;
        float wy[4], wx[4];
        int ry[4], cx[4];
#pragma unroll
        for (int k = 0; k < 4; ++k) {
            float fy = (gy0 + k + 0.5f) * 0.5f - 0.5f;
            float fl = floorf(fy);
            wy[k] = fy - fl; ry[k] = (int)fl - baseY[0];
            float fx = (gx0 + k + 0.5f) * 0.5f - 0.5f;
            fl = floorf(fx);
            wx[k] = fx - fl; cx[k] = (int)fl - baseX[0];
        }
        const int r0 = ry[0], c0 = cx[0];
        const float* pp = patch + r0 * dim + c0;
        float P[4][4];
#pragma unroll
        for (int r = 0; r < 4; ++r)
#pragma unroll
            for (int c = 0; c < 4; ++c) P[r][c] = pp[r * dim + c];
        float h[4][4];
#pragma unroll
        for (int j = 0; j < 4; ++j) {
            int dx = cx[j] - c0;
#pragma unroll
            for (int r = 0; r < 4; ++r) {
                float a = dx == 0 ? P[r][0] : (dx == 1 ? P[r][1] : P[r][2]);
                float bb = dx == 0 ? P[r][1] : (dx == 1 ? P[r][2] : P[r][3]);
                h[r][j] = a + wx[j] * (bb - a);
            }
        }
#pragma unroll
        for (int i = 0; i < 4; ++i) {
            int dy = ry[i] - r0;
#pragma unroll
            for (int j = 0; j < 4; ++j) {
                float h0 = dy == 0 ? h[0][j] : (dy == 1 ? h[1][j] : h[2][j]);
                float h1 = dy == 0 ? h[1][j] : (dy == 1 ? h[2][j] : h[3][j]);
                acc[i][j] += h0 + wy[i] * (h1 - h0);
            }
        }
    }
    // ---- levels 1..6 (scale <= 1/4): 3x3 register patch ----
#pragma unroll
    for (int li = 1; li < 7; ++li) {
        const int dim = dims[li];
        const float* P0 = patch + lofs[li];
        const float s = 1.f / (float)(2 << li);
        float wy[4], wx[4];
        int ry[4], cx[4];
#pragma unroll
        for (int k = 0; k < 4; ++k) {
            float fy = (gy0 + k + 0.5f) * s - 0.5f;
            float fl = floorf(fy);
            wy[k] = fy - fl; ry[k] = (int)fl - baseY[li];
            float fx = (gx0 + k + 0.5f) * s - 0.5f;
            fl = floorf(fx);
            wx[k] = fx - fl; cx[k] = (int)fl - baseX[li];
        }
        const int r0 = ry[0], c0 = cx[0];
        const float* pp = P0 + r0 * dim + c0;
        float P[3][3];
#pragma unroll
        for (int r = 0; r < 3; ++r)
#pragma unroll
            for (int c = 0; c < 3; ++c) P[r][c] = pp[r * dim + c];
        float h[3][4];
#pragma unroll
        for (int j = 0; j < 4; ++j) {
            int dx = cx[j] - c0;
#pragma unroll
            for (int r = 0; r < 3; ++r) {
                float a = dx == 0 ? P[r][0] : P[r][1];
                float bb = dx == 0 ? P[r][1] : P[r][2];
                h[r][j] = a + wx[j] * (bb - a);
            }
        }
#pragma unroll
        for (int i = 0; i < 4; ++i) {
            int dy = ry[i] - r0;
#pragma unroll
            for (int j = 0; j < 4; ++j) {
                float h0 = dy == 0 ? h[0][j] : h[1][j];
                float h1 = dy == 0 ? h[1][j] : h[2][j];
                acc[i][j] += h0 + wy[i] * (h1 - h0);
            }
        }
    }

    const float bt = sBtot;
    float* op = out + ((size_t)b * 512 + gy0) * 512 + gx0;
#pragma unroll
    for (int i = 0; i < 4; ++i) {
        float4 v;
        v.x = (acc[i][0] + bt) * (1.f / 3.f);
        v.y = (acc[i][1] + bt) * (1.f / 3.f);
        v.z = (acc[i][2] + bt) * (1.f / 3.f);
        v.w = (acc[i][3] + bt) * (1.f / 3.f);
        *(float4*)(op + (size_t)i * 512) = v;
    }
}

extern "C" void kernel_launch(void* const* d_in, const int* in_sizes, int n_in,
                              void* d_out, int out_size, void* d_ws, size_t ws_size,
                              hipStream_t stream) {
    (void)in_sizes; (void)n_in; (void)out_size; (void)ws_size;
    const float* x = (const float*)d_in[0];
    float* ws = (float*)d_ws;
    float* out = (float*)d_out;

    // Workspace layout (float offsets):
    float* pyr1 = ws;                  // 256^2*24 = 1572864
    float* pyr3 = ws + 1572864;        //  64^2*24 =   98304
    float* dBase = ws + 1671168;       // d0..d6   = 2097024
    float* tmin0 = ws + 3768192;       // 6144
    float* tmax0 = ws + 3774336;       // 6144
    float* tmin1 = ws + 3780480;       // 1536
    float* tmax1 = ws + 3782016;       // 1536
    float* A = ws + 3783552;           // 168
    float* Bc = ws + 3783720;          // 168
    int* ctr = (int*)(ws + 3783888);   // 24 ints (zeroed below; ws is poisoned)

    hipMemsetAsync(ctr, 0, NPLANES * sizeof(int), stream);
    // Level 1 from raw x (initial _norm_pc is an affine no-op for the output)
    pyrdown_l1<<<NPLANES * 64, 256, 0, stream>>>(x, pyr1);
    pyrdown23<<<NPLANES * 16, 256, 0, stream>>>(pyr1, pyr3, dBase, tmin0, tmax0,
                                                tmin1, tmax1, A, Bc, ctr);
    final_kernel<<<8 * 64, 256, 0, stream>>>(dBase, A, Bc, out);
}

// Round 11
// 103.477 us; speedup vs baseline: 1.4740x; 1.4740x over previous
//
#include <hip/hip_runtime.h>
#include <math.h>

#define NPLANES 24   // B*C = 8*3
#define FINF 3.402823466e38f

__host__ __device__ __forceinline__ int d_off(int li) {
    return 2097152 - (2097152 >> (2 * li));
}

__device__ __forceinline__ int refl(int v, int S) {
    if (v < 0) v = -v;
    if (v >= S) v = 2 * S - 2 - v;
    return v;
}

// ---- shuffle reductions (no LDS, no barriers) ----
__device__ __forceinline__ void wminmax64(float& mn, float& mx) {
#pragma unroll
    for (int o = 32; o > 0; o >>= 1) {
        mn = fminf(mn, __shfl_xor(mn, o, 64));
        mx = fmaxf(mx, __shfl_xor(mx, o, 64));
    }
}
__device__ __forceinline__ float wsumx64(float v) {
#pragma unroll
    for (int o = 32; o > 0; o >>= 1) v += __shfl_xor(v, o, 64);
    return v;
}
__device__ __forceinline__ void wminmax16(float& mn, float& mx) {
#pragma unroll
    for (int o = 8; o > 0; o >>= 1) {
        mn = fminf(mn, __shfl_xor(mn, o, 16));
        mx = fmaxf(mx, __shfl_xor(mx, o, 16));
    }
}

// 6-tap separable collapsed pyrdown stencil on an LDS plane of size SxS.
__device__ __forceinline__ float stencil6(const float* s, int S, int i, int j) {
    const float w[6] = {1.f, 5.f, 10.f, 10.f, 5.f, 1.f};
    int rx[6];
#pragma unroll
    for (int b = 0; b < 6; ++b) rx[b] = refl(2 * j - 2 + b, S);
    float acc = 0.f;
#pragma unroll
    for (int a = 0; a < 6; ++a) {
        int ry = refl(2 * i - 2 + a, S);
        const float* rp = s + ry * S;
        float r = 0.f;
#pragma unroll
        for (int b = 0; b < 6; ++b) r += w[b] * rp[rx[b]];
        acc += w[a] * r;
    }
    return acc * (1.f / 1024.f);
}

// L1 pyrdown: x (512^2) -> pyr1 (256^2). Block = 32x32 output tile.
__global__ __launch_bounds__(256) void pyrdown_l1(const float* __restrict__ in,
                                                  float* __restrict__ out) {
    constexpr int IS = 512, SO = 256, TO = 32, TI = 68, TPA = 8;
    __shared__ float sIn[TI * TI];
    __shared__ float sH[TI * TO];
    const int tid = threadIdx.x;
    const int p = blockIdx.x / (TPA * TPA);
    const int t = blockIdx.x % (TPA * TPA);
    const int ty = t / TPA, tx = t % TPA;
    const int oy = ty * TO, ox = tx * TO;
    const int iy = 2 * oy - 2, ix = 2 * ox - 2;
    const float* ip = in + (size_t)p * IS * IS;

    for (int k = tid; k < TI * TI; k += 256) {
        int r = k / TI, c = k - r * TI;
        sIn[k] = ip[refl(iy + r, IS) * IS + refl(ix + c, IS)];
    }
    __syncthreads();
    for (int k = tid; k < TI * 8; k += 256) {
        int r = k >> 3, jq = k & 7;
        const float4* rp = (const float4*)(sIn + r * TI + 8 * jq);
        float4 v0 = rp[0], v1 = rp[1], v2 = rp[2];
        float4 o;
        o.x = v0.x + 5.f * v0.y + 10.f * v0.z + 10.f * v0.w + 5.f * v1.x + v1.y;
        o.y = v0.z + 5.f * v0.w + 10.f * v1.x + 10.f * v1.y + 5.f * v1.z + v1.w;
        o.z = v1.x + 5.f * v1.y + 10.f * v1.z + 10.f * v1.w + 5.f * v2.x + v2.y;
        o.w = v1.z + 5.f * v1.w + 10.f * v2.x + 10.f * v2.y + 5.f * v2.z + v2.w;
        *(float4*)(sH + r * TO + 4 * jq) = o;
    }
    __syncthreads();
    {
        int i = tid >> 3, jq = tid & 7;
        const float* base = sH + (2 * i) * TO + 4 * jq;
        float4 r0 = *(const float4*)(base);
        float4 r1 = *(const float4*)(base + TO);
        float4 r2 = *(const float4*)(base + 2 * TO);
        float4 r3 = *(const float4*)(base + 3 * TO);
        float4 r4 = *(const float4*)(base + 4 * TO);
        float4 r5 = *(const float4*)(base + 5 * TO);
        float4 o;
        o.x = (r0.x + 5.f * r1.x + 10.f * r2.x + 10.f * r3.x + 5.f * r4.x + r5.x) * (1.f / 1024.f);
        o.y = (r0.y + 5.f * r1.y + 10.f * r2.y + 10.f * r3.y + 5.f * r4.y + r5.y) * (1.f / 1024.f);
        o.z = (r0.z + 5.f * r1.z + 10.f * r2.z + 10.f * r3.z + 5.f * r4.z + r5.z) * (1.f / 1024.f);
        o.w = (r0.w + 5.f * r1.w + 10.f * r2.w + 10.f * r3.w + 5.f * r4.w + r5.w) * (1.f / 1024.f);
        *(float4*)(out + (size_t)p * SO * SO + (size_t)(oy + i) * SO + ox + 4 * jq) = o;
    }
}

// Fused L2+L3 pyrdown (R9 structure, no device-scope fences). Block = one
// 16x16 pyr3 tile; grid = 24 planes x 16 tiles = 384 blocks.
__global__ __launch_bounds__(256) void pyrdown23(const float* __restrict__ pyr1,
                                                 float* __restrict__ pyr3,
                                                 float* __restrict__ dBase,
                                                 float* __restrict__ tmin0,
                                                 float* __restrict__ tmax0,
                                                 float* __restrict__ tmin1,
                                                 float* __restrict__ tmax1) {
    __shared__ float sIn[5776];   // 76x76 pyr1 patch (reflect-staged)
    __shared__ float sH1[2736];   // 76x36
    __shared__ float sP2[1296];   // 36x36 pyr2 patch
    __shared__ float sH2[576];    // 36x16
    __shared__ float sP3t[256];   // 16x16
    const int tid = threadIdx.x;
    const int p = blockIdx.x >> 4;
    const int t = blockIdx.x & 15;
    const int t3y = t >> 2, t3x = t & 3;
    const int oy3 = t3y * 16, ox3 = t3x * 16;
    const int oy2 = 2 * oy3, ox2 = 2 * ox3;
    const int py0 = oy2 - 2, px0 = ox2 - 2;
    const int iy0 = 2 * py0 - 2, ix0 = 2 * px0 - 2;
    const float* ip = pyr1 + (size_t)p * 65536;

    for (int k = tid; k < 5776; k += 256) {
        int r = k / 76, c = k - r * 76;
        sIn[k] = ip[refl(iy0 + r, 256) * 256 + refl(ix0 + c, 256)];
    }
    __syncthreads();
    // h1: column pairs -> two aligned ds_read_b128 per 2 outputs (conflict-free;
    // identical operand order to the scalar stride-2 version)
    for (int k = tid; k < 1368; k += 256) {
        int r = k / 18, m = k - r * 18;
        const float4* rp = (const float4*)(sIn + r * 76 + 4 * m);
        float4 v0 = rp[0], v1 = rp[1];
        float o0 = v0.x + 5.f * v0.y + 10.f * v0.z + 10.f * v0.w + 5.f * v1.x + v1.y;
        float o1 = v0.z + 5.f * v0.w + 10.f * v1.x + 10.f * v1.y + 5.f * v1.z + v1.w;
        float2 o2; o2.x = o0; o2.y = o1;
        *(float2*)(sH1 + r * 36 + 2 * m) = o2;
    }
    __syncthreads();
    // v1 -> sP2 (36x36)
    for (int k = tid; k < 1296; k += 256) {
        int r2 = k / 36, c2 = k - r2 * 36;
        const float* cp = sH1 + 2 * r2 * 36 + c2;
        sP2[k] = (cp[0] + 5.f * cp[36] + 10.f * cp[72] + 10.f * cp[108] +
                  5.f * cp[144] + cp[180]) * (1.f / 1024.f);
    }
    __syncthreads();
    // h2: 36 rows x 16 pyr3-cols, reflect pyr2 col index at S=128
    for (int k = tid; k < 576; k += 256) {
        int r2 = k >> 4, c3 = k & 15;
        int gb = 2 * (ox3 + c3) - 2;
        const float* rp = sP2 + r2 * 36;
        sH2[k] = rp[refl(gb, 128) - px0] + 5.f * rp[refl(gb + 1, 128) - px0] +
                 10.f * rp[refl(gb + 2, 128) - px0] + 10.f * rp[refl(gb + 3, 128) - px0] +
                 5.f * rp[refl(gb + 4, 128) - px0] + rp[refl(gb + 5, 128) - px0];
    }
    __syncthreads();
    // v2 -> sP3t + global pyr3
    {
        int i3 = tid >> 4, c3 = tid & 15;
        int gb = 2 * (oy3 + i3) - 2;
        float s = sH2[(refl(gb, 128) - py0) * 16 + c3] +
                  5.f * sH2[(refl(gb + 1, 128) - py0) * 16 + c3] +
                  10.f * sH2[(refl(gb + 2, 128) - py0) * 16 + c3] +
                  10.f * sH2[(refl(gb + 3, 128) - py0) * 16 + c3] +
                  5.f * sH2[(refl(gb + 4, 128) - py0) * 16 + c3] +
                  sH2[(refl(gb + 5, 128) - py0) * 16 + c3];
        float v = s * (1.f / 1024.f);
        sP3t[tid] = v;
        pyr3[(size_t)p * 4096 + (size_t)(oy3 + i3) * 64 + ox3 + c3] = v;
    }
    __syncthreads();
    // d0 = |pyr1 - up(pyr2)|, 4x4 block/thread; 16x16 stats tile = 16 threads
    {
        float* d0g = dBase + (size_t)p * 65536;
        int ti = tid >> 4, si = tid & 15;
        int tr = ti >> 2, tc = ti & 3;
        int y0 = tr * 16 + (si >> 2) * 4, x0 = tc * 16 + (si & 3) * 4;
        float mn = FINF, mx = -FINF;
#pragma unroll
        for (int r = 0; r < 4; ++r) {
            int y = y0 + r;
            const float* srow = sIn + (y + 6) * 76 + x0 + 6;
            const float* prow = sP2 + ((y >> 1) + 2) * 36 + 2 + (x0 >> 1);
            float e0 = prow[0], e1 = prow[1];
            float4 dv;
            dv.x = fabsf(srow[0] - e0);
            dv.y = fabsf(srow[1] - e0);
            dv.z = fabsf(srow[2] - e1);
            dv.w = fabsf(srow[3] - e1);
            *(float4*)(d0g + (size_t)(4 * oy3 + y) * 256 + 4 * ox3 + x0) = dv;
            mn = fminf(mn, fminf(fminf(dv.x, dv.y), fminf(dv.z, dv.w)));
            mx = fmaxf(mx, fmaxf(fmaxf(dv.x, dv.y), fmaxf(dv.z, dv.w)));
        }
        wminmax16(mn, mx);
        if (si == 0) {
            int g0 = p * 256 + (t3y * 4 + tr) * 16 + (t3x * 4 + tc);
            tmin0[g0] = mn;
            tmax0[g0] = mx;
        }
    }
    // d1 = |pyr2 - up(pyr3)|, wave 0 only
    if (tid < 64) {
        float* d1g = dBase + d_off(1) + (size_t)p * 16384;
        int ti = tid >> 4, si = tid & 15;
        int tr = ti >> 1, tc = ti & 1;
        int y0 = tr * 16 + (si >> 2) * 4, x0 = tc * 16 + (si & 3) * 4;
        float mn = FINF, mx = -FINF;
#pragma unroll
        for (int r = 0; r < 4; ++r) {
            int y = y0 + r;
            const float* prow = sP2 + (y + 2) * 36 + 2 + x0;
            const float* qrow = sP3t + (y >> 1) * 16 + (x0 >> 1);
            float e0 = qrow[0], e1 = qrow[1];
            float4 dv;
            dv.x = fabsf(prow[0] - e0);
            dv.y = fabsf(prow[1] - e0);
            dv.z = fabsf(prow[2] - e1);
            dv.w = fabsf(prow[3] - e1);
            *(float4*)(d1g + (size_t)(oy2 + y) * 128 + ox2 + x0) = dv;
            mn = fminf(mn, fminf(fminf(dv.x, dv.y), fminf(dv.z, dv.w)));
            mx = fmaxf(mx, fmaxf(fmaxf(dv.x, dv.y), fmaxf(dv.z, dv.w)));
        }
        wminmax16(mn, mx);
        if (si == 0) {
            int g1 = p * 64 + (t3y * 2 + tr) * 8 + (t3x * 2 + tc);
            tmin1[g1] = mn;
            tmax1[g1] = mx;
        }
    }
}

// One block (1024 threads) per plane, barrier-light (R9-verified).
__global__ __launch_bounds__(1024) void fused_small_kernel(const float* __restrict__ pyr3,
                                                           float* __restrict__ dBase,
                                                           const float* __restrict__ tmin0,
                                                           const float* __restrict__ tmax0,
                                                           const float* __restrict__ tmin1,
                                                           const float* __restrict__ tmax1,
                                                           float* __restrict__ A,
                                                           float* __restrict__ B) {
    __shared__ float sP3[4096];
    __shared__ float sd2[4096];
    __shared__ float sp4[1024], sd3[1024];
    __shared__ float sp5[256], sd4[256];
    __shared__ float sp6[64], sd5[64];
    __shared__ float sp7[16], sd6[16];
    const int tid = threadIdx.x;
    const int p = blockIdx.x;

    if (tid < 1024) ((float4*)sP3)[tid] = ((const float4*)(pyr3 + (size_t)p * 4096))[tid];
    __syncthreads();
    // stage A: pyr4 (32x32) + d2 (64x64), one pyr4 output per thread
    {
        float* d2g = dBase + d_off(2) + (size_t)p * 4096;
        int i = tid >> 5, j = tid & 31;
        float v = stencil6(sP3, 64, i, j);
        sp4[tid] = v;
#pragma unroll
        for (int di = 0; di < 2; ++di)
#pragma unroll
            for (int dj = 0; dj < 2; ++dj) {
                int y = 2 * i + di, x = 2 * j + dj;
                float dv = fabsf(sP3[y * 64 + x] - v);
                sd2[y * 64 + x] = dv;
                d2g[y * 64 + x] = dv;
            }
    }
    __syncthreads();

    const int wave = tid >> 6, lane = tid & 63;

    // ---- stage B: specialized waves, no internal barriers ----
    if (wave == 0) {
        float* d3g = dBase + d_off(3) + (size_t)p * 1024;
#pragma unroll
        for (int q = 0; q < 4; ++q) {
            int k = lane + 64 * q;
            int i = k >> 4, j = k & 15;
            float v = stencil6(sp4, 32, i, j);
            sp5[k] = v;
#pragma unroll
            for (int di = 0; di < 2; ++di)
#pragma unroll
                for (int dj = 0; dj < 2; ++dj) {
                    int y = 2 * i + di, x = 2 * j + dj;
                    float dv = fabsf(sp4[y * 32 + x] - v);
                    sd3[y * 32 + x] = dv;
                    d3g[y * 32 + x] = dv;
                }
        }
        {
            int i = lane >> 3, j = lane & 7;
            float v = stencil6(sp5, 16, i, j);
            sp6[lane] = v;
            float* d4g = dBase + d_off(4) + (size_t)p * 256;
#pragma unroll
            for (int di = 0; di < 2; ++di)
#pragma unroll
                for (int dj = 0; dj < 2; ++dj) {
                    int y = 2 * i + di, x = 2 * j + dj;
                    float dv = fabsf(sp5[y * 16 + x] - v);
                    sd4[y * 16 + x] = dv;
                    d4g[y * 16 + x] = dv;
                }
        }
        if (lane < 16) {
            int i = lane >> 2, j = lane & 3;
            float v = stencil6(sp6, 8, i, j);
            sp7[lane] = v;
            float* d5g = dBase + d_off(5) + (size_t)p * 64;
#pragma unroll
            for (int di = 0; di < 2; ++di)
#pragma unroll
                for (int dj = 0; dj < 2; ++dj) {
                    int y = 2 * i + di, x = 2 * j + dj;
                    float dv = fabsf(sp6[y * 8 + x] - v);
                    sd5[y * 8 + x] = dv;
                    d5g[y * 8 + x] = dv;
                }
        }
        if (lane < 4) {
            int i = lane >> 1, j = lane & 1;
            float v = stencil6(sp7, 4, i, j);
            float* d6g = dBase + d_off(6) + (size_t)p * 16;
#pragma unroll
            for (int di = 0; di < 2; ++di)
#pragma unroll
                for (int dj = 0; dj < 2; ++dj) {
                    int y = 2 * i + di, x = 2 * j + dj;
                    float dv = fabsf(sp7[y * 4 + x] - v);
                    sd6[y * 4 + x] = dv;
                    d6g[y * 4 + x] = dv;
                }
        }
    } else if (wave == 1) {
        // li=1 reduce from tile stats (64 tiles, interior 7x7)
        float tmn = tmin1[p * 64 + lane];
        float tmx = tmax1[p * 64 + lane];
        float mn = tmn, mx = tmx;
        wminmax64(mn, mx);
        float su = ((lane >> 3) < 7 && (lane & 7) < 7) ? tmx : 0.f;
        float sum = wsumx64(su);
        if (lane == 0) {
            float inv = 1.f / (mx - mn);
            float lm = (sum * (1.f / 49.f) - mn) * inv;
            float g = (1.f - lm) * (1.f - lm);
            A[1 * NPLANES + p] = g * inv;
            B[1 * NPLANES + p] = -mn * g * inv;
        }
    } else if (wave == 2) {
        // li=0 reduce from tile stats (256 tiles, interior 15x15)
        float mn = FINF, mx = -FINF, su = 0.f;
#pragma unroll
        for (int q = 0; q < 4; ++q) {
            int t = lane + 64 * q;
            float tmn = tmin0[p * 256 + t];
            float tmx = tmax0[p * 256 + t];
            mn = fminf(mn, tmn);
            mx = fmaxf(mx, tmx);
            if ((t >> 4) < 15 && (t & 15) < 15) su += tmx;
        }
        wminmax64(mn, mx);
        float sum = wsumx64(su);
        if (lane == 0) {
            float inv = 1.f / (mx - mn);
            float lm = (sum * (1.f / 225.f) - mn) * inv;
            float g = (1.f - lm) * (1.f - lm);
            A[0 * NPLANES + p] = g * inv;
            B[0 * NPLANES + p] = -mn * g * inv;
        }
    }
    __syncthreads();

    // ---- stage C: one wave per level, shuffle-only stats ----
    if (wave == 0) {
        // li=2: sd2 (64x64), interior 3x3 tiles
        const float4* sv = (const float4*)sd2;
        float mn = FINF, mx = -FINF;
#pragma unroll
        for (int q = 0; q < 16; ++q) {
            float4 v = sv[lane + 64 * q];
            mn = fminf(mn, fminf(fminf(v.x, v.y), fminf(v.z, v.w)));
            mx = fmaxf(mx, fmaxf(fmaxf(v.x, v.y), fmaxf(v.z, v.w)));
        }
        wminmax64(mn, mx);
        float tmax = -FINF;
        if (lane < 36) {
            int t = lane >> 2, r4 = lane & 3;
            int tr = t / 3, tc = t % 3;
#pragma unroll
            for (int rr = 0; rr < 4; ++rr) {
                const float4* base = (const float4*)(sd2 + (16 * tr + 4 * r4 + rr) * 64 + 16 * tc);
#pragma unroll
                for (int c = 0; c < 4; ++c) {
                    float4 v = base[c];
                    tmax = fmaxf(tmax, fmaxf(fmaxf(v.x, v.y), fmaxf(v.z, v.w)));
                }
            }
        }
        tmax = fmaxf(tmax, __shfl_xor(tmax, 1, 64));
        tmax = fmaxf(tmax, __shfl_xor(tmax, 2, 64));
        float val = ((lane & 3) == 0 && lane < 36) ? tmax : 0.f;
        float s = wsumx64(val);
        if (lane == 0) {
            float inv = 1.f / (mx - mn);
            float lm = (s * (1.f / 9.f) - mn) * inv;
            float g = (1.f - lm) * (1.f - lm);
            A[2 * NPLANES + p] = g * inv;
            B[2 * NPLANES + p] = -mn * g * inv;
        }
    } else if (wave == 1) {
        // li=3: sd3 (32x32), single interior 16x16 tile
        const float4* sv = (const float4*)sd3;
        float mn = FINF, mx = -FINF;
#pragma unroll
        for (int q = 0; q < 4; ++q) {
            float4 v = sv[lane + 64 * q];
            mn = fminf(mn, fminf(fminf(v.x, v.y), fminf(v.z, v.w)));
            mx = fmaxf(mx, fmaxf(fmaxf(v.x, v.y), fmaxf(v.z, v.w)));
        }
        wminmax64(mn, mx);
        float4 e4 = sv[(lane >> 2) * 8 + (lane & 3)];
        float e = fmaxf(fmaxf(e4.x, e4.y), fmaxf(e4.z, e4.w));
        float tn = e, tm = e;
        wminmax64(tn, tm);
        if (lane == 0) {
            float inv = 1.f / (mx - mn);
            float lm = (tm - mn) * inv;
            float g = (1.f - lm) * (1.f - lm);
            A[3 * NPLANES + p] = g * inv;
            B[3 * NPLANES + p] = -mn * g * inv;
        }
    } else if (wave == 2) {
        float4 v = ((const float4*)sd4)[lane];
        float mn = fminf(fminf(v.x, v.y), fminf(v.z, v.w));
        float mx = fmaxf(fmaxf(v.x, v.y), fmaxf(v.z, v.w));
        wminmax64(mn, mx);
        if (lane == 0) {
            float inv = 1.f / (mx - mn);
            A[4 * NPLANES + p] = inv; B[4 * NPLANES + p] = -mn * inv;
        }
    } else if (wave == 3) {
        float v = sd5[lane];
        float mn = v, mx = v;
        wminmax64(mn, mx);
        if (lane == 0) {
            float inv = 1.f / (mx - mn);
            A[5 * NPLANES + p] = inv; B[5 * NPLANES + p] = -mn * inv;
        }
    } else if (wave == 4) {
        float v = (lane < 16) ? sd6[lane] : sd6[0];
        float mn = v, mx = v;
        wminmax64(mn, mx);
        if (lane == 0) {
            float inv = 1.f / (mx - mn);
            A[6 * NPLANES + p] = inv; B[6 * NPLANES + p] = -mn * inv;
        }
    }
}

// Tiled final gather, register-patch bilerp (R6-verified).
__global__ __launch_bounds__(256) void final_kernel(const float* __restrict__ dBase,
                                                    const float* __restrict__ A,
                                                    const float* __restrict__ Bc,
                                                    float* __restrict__ out) {
    __shared__ float patch[1700];
    __shared__ float sBtot;
    const int tid = threadIdx.x;
    const int b = blockIdx.x >> 6;
    const int tile = blockIdx.x & 63;
    const int yb = (tile >> 3) << 6;
    const int xb = (tile & 7) << 6;

    if (tid == 0) {
        float s = 0.f;
        for (int k = 0; k < 7; ++k)
            for (int c = 0; c < 3; ++c) s += Bc[k * NPLANES + b * 3 + c];
        sBtot = s;
    }

    const int dims[7] = {34, 18, 10, 6, 4, 3, 3};
    const int lofs[7] = {0, 1156, 1480, 1580, 1616, 1632, 1641};
    int baseY[7], baseX[7];
#pragma unroll
    for (int li = 0; li < 7; ++li) {
        const int S = 256 >> li;
        const float s = 1.f / (float)(2 << li);
        baseY[li] = (int)floorf((yb + 0.5f) * s - 0.5f);
        baseX[li] = (int)floorf((xb + 0.5f) * s - 0.5f);
        const int dim = dims[li];
        const int n = dim * dim;
        const float* d0p = dBase + d_off(li) + (size_t)(b * 3) * S * S;
        const float* d1p = d0p + S * S;
        const float* d2p = d1p + S * S;
        const float A0 = A[li * NPLANES + b * 3 + 0];
        const float A1 = A[li * NPLANES + b * 3 + 1];
        const float A2 = A[li * NPLANES + b * 3 + 2];
        for (int k = tid; k < n; k += 256) {
            int r = k / dim, c = k - r * dim;
            int sr = min(max(baseY[li] + r, 0), S - 1);
            int sc = min(max(baseX[li] + c, 0), S - 1);
            int si = sr * S + sc;
            patch[lofs[li] + k] = A0 * d0p[si] + A1 * d1p[si] + A2 * d2p[si];
        }
    }
    __syncthreads();

    const int ty = tid >> 4, tx = tid & 15;
    const int gy0 = yb + (ty << 2), gx0 = xb + (tx << 2);
    float acc[4][4];
#pragma unroll
    for (int i = 0; i < 4; ++i)
#pragma unroll
        for (int j = 0; j < 4; ++j) acc[i][j] = 0.f;

    // ---- level 0 (scale 1/2): 4x4 register patch ----
    {
        const int dim = 34;
        float wy[4], wx[4];
        int ry[4], cx[4];
#pragma unroll
        for (int k = 0; k < 4; ++k) {
            float fy = (gy0 + k + 0.5f) * 0.5f - 0.5f;
            float fl = floorf(fy);
            wy[k] = fy - fl; ry[k] = (int)fl - baseY[0];
            float fx = (gx0 + k + 0.5f) * 0.5f - 0.5f;
            fl = floorf(fx);
            wx[k] = fx - fl; cx[k] = (int)fl - baseX[0];
        }
        const int r0 = ry[0], c0 = cx[0];
        const float* pp = patch + r0 * dim + c0;
        float P[4][4];
#pragma unroll
        for (int r = 0; r < 4; ++r)
#pragma unroll
            for (int c = 0; c < 4; ++c) P[r][c] = pp[r * dim + c];
        float h[4][4];
#pragma unroll
        for (int j = 0; j < 4; ++j) {
            int dx = cx[j] - c0;
#pragma unroll
            for (int r = 0; r < 4; ++r) {
                float a = dx == 0 ? P[r][0] : (dx == 1 ? P[r][1] : P[r][2]);
                float bb = dx == 0 ? P[r][1] : (dx == 1 ? P[r][2] : P[r][3]);
                h[r][j] = a + wx[j] * (bb - a);
            }
        }
#pragma unroll
        for (int i = 0; i < 4; ++i) {
            int dy = ry[i] - r0;
#pragma unroll
            for (int j = 0; j < 4; ++j) {
                float h0 = dy == 0 ? h[0][j] : (dy == 1 ? h[1][j] : h[2][j]);
                float h1 = dy == 0 ? h[1][j] : (dy == 1 ? h[2][j] : h[3][j]);
                acc[i][j] += h0 + wy[i] * (h1 - h0);
            }
        }
    }
    // ---- levels 1..6 (scale <= 1/4): 3x3 register patch ----
#pragma unroll
    for (int li = 1; li < 7; ++li) {
        const int dim = dims[li];
        const float* P0 = patch + lofs[li];
        const float s = 1.f / (float)(2 << li);
        float wy[4], wx[4];
        int ry[4], cx[4];
#pragma unroll
        for (int k = 0; k < 4; ++k) {
            float fy = (gy0 + k + 0.5f) * s - 0.5f;
            float fl = floorf(fy);
            wy[k] = fy - fl; ry[k] = (int)fl - baseY[li];
            float fx = (gx0 + k + 0.5f) * s - 0.5f;
            fl = floorf(fx);
            wx[k] = fx - fl; cx[k] = (int)fl - baseX[li];
        }
        const int r0 = ry[0], c0 = cx[0];
        const float* pp = P0 + r0 * dim + c0;
        float P[3][3];
#pragma unroll
        for (int r = 0; r < 3; ++r)
#pragma unroll
            for (int c = 0; c < 3; ++c) P[r][c] = pp[r * dim + c];
        float h[3][4];
#pragma unroll
        for (int j = 0; j < 4; ++j) {
            int dx = cx[j] - c0;
#pragma unroll
            for (int r = 0; r < 3; ++r) {
                float a = dx == 0 ? P[r][0] : P[r][1];
                float bb = dx == 0 ? P[r][1] : P[r][2];
                h[r][j] = a + wx[j] * (bb - a);
            }
        }
#pragma unroll
        for (int i = 0; i < 4; ++i) {
            int dy = ry[i] - r0;
#pragma unroll
            for (int j = 0; j < 4; ++j) {
                float h0 = dy == 0 ? h[0][j] : h[1][j];
                float h1 = dy == 0 ? h[1][j] : h[2][j];
                acc[i][j] += h0 + wy[i] * (h1 - h0);
            }
        }
    }

    const float bt = sBtot;
    float* op = out + ((size_t)b * 512 + gy0) * 512 + gx0;
#pragma unroll
    for (int i = 0; i < 4; ++i) {
        float4 v;
        v.x = (acc[i][0] + bt) * (1.f / 3.f);
        v.y = (acc[i][1] + bt) * (1.f / 3.f);
        v.z = (acc[i][2] + bt) * (1.f / 3.f);
        v.w = (acc[i][3] + bt) * (1.f / 3.f);
        *(float4*)(op + (size_t)i * 512) = v;
    }
}

extern "C" void kernel_launch(void* const* d_in, const int* in_sizes, int n_in,
                              void* d_out, int out_size, void* d_ws, size_t ws_size,
                              hipStream_t stream) {
    (void)in_sizes; (void)n_in; (void)out_size; (void)ws_size;
    const float* x = (const float*)d_in[0];
    float* ws = (float*)d_ws;
    float* out = (float*)d_out;

    // Workspace layout (float offsets):
    float* pyr1 = ws;                  // 256^2*24 = 1572864
    float* pyr3 = ws + 1572864;        //  64^2*24 =   98304
    float* dBase = ws + 1671168;       // d0..d6   = 2097024
    float* tmin0 = ws + 3768192;       // 6144
    float* tmax0 = ws + 3774336;       // 6144
    float* tmin1 = ws + 3780480;       // 1536
    float* tmax1 = ws + 3782016;       // 1536
    float* A = ws + 3783552;           // 168
    float* Bc = ws + 3783720;          // 168

    // Level 1 from raw x (initial _norm_pc is an affine no-op for the output)
    pyrdown_l1<<<NPLANES * 64, 256, 0, stream>>>(x, pyr1);
    pyrdown23<<<NPLANES * 16, 256, 0, stream>>>(pyr1, pyr3, dBase, tmin0, tmax0, tmin1, tmax1);
    fused_small_kernel<<<NPLANES, 1024, 0, stream>>>(pyr3, dBase, tmin0, tmax0, tmin1, tmax1, A, Bc);
    final_kernel<<<8 * 64, 256, 0, stream>>>(dBase, A, Bc, out);
}